// Round 5
// baseline (516.649 us; speedup 1.0000x reference)
//
#include <hip/hip_runtime.h>

// GumbelSlotSelector R5: identical structure to R4 (MFMA 3x-bf16-split exact
// fp32 GEMM, serialized mt, 1-step prefetch, shuffle epilogue, ballot fixup).
// ONE change: union type-puns -> __builtin_bit_cast (no-op vector bitcast),
// eliminating the per-thread scratch round-trip (R4: 486 MB spurious WRITE).

typedef __attribute__((ext_vector_type(8))) short bf16x8;
typedef __attribute__((ext_vector_type(4))) int   i32x4;
typedef __attribute__((ext_vector_type(4))) float f32x4;

constexpr int NROWS = 8192 * 64;   // 524288
constexpr int D = 128;

__device__ __forceinline__ void split3(float x, unsigned& h1, unsigned& h2, unsigned& h3) {
    unsigned ux = __float_as_uint(x);
    h1 = ux & 0xFFFF0000u;                    // top bf16 (truncate) — exact subtract
    float r = x - __uint_as_float(h1);
    h2 = __float_as_uint(r) & 0xFFFF0000u;    // next 8 mantissa bits
    float r2 = r - __uint_as_float(h2);
    h3 = __float_as_uint(r2);                 // remaining bits (high 16 used)
}

__device__ __forceinline__ int pack2(unsigned hx, unsigned hy) {
    return (int)((hx >> 16) | (hy & 0xFFFF0000u));   // [x bf16 | y bf16]
}

__global__ __launch_bounds__(512, 4)
void gumbel_slot_mfma(const float* __restrict__ slots,
                      const float* __restrict__ gumbel_u,
                      const float* __restrict__ fix_u,
                      const float* __restrict__ W1,
                      const float* __restrict__ b1,
                      const float* __restrict__ W2,
                      const float* __restrict__ b2,
                      float* __restrict__ out)
{
    // W1 3-split bf16, j-major [plane][j=64][d=128], 16B chunks XOR-swizzled
    // by (j&15) — layout/read path proven in R2-R4.
    __shared__ __align__(16) unsigned short wt[3 * 64 * 128];   // 48 KB

    const int tid  = threadIdx.x;
    const int wv   = tid >> 6;
    const int lane = tid & 63;
    const int quad = lane >> 4;
    const int col  = lane & 15;

    // ---- one-time W1 split prep (the only __syncthreads in the kernel) ----
#pragma unroll
    for (int i = 0; i < 16; ++i) {
        const int e = i * 512 + tid;         // e = d*64 + j, coalesced
        const int d = e >> 6, j = e & 63;
        unsigned h1, h2, h3;
        split3(W1[e], h1, h2, h3);
        const int chunk = (d >> 3) ^ (j & 15);
        const int idx = j * 128 + chunk * 8 + (d & 7);
        wt[idx]         = (unsigned short)(h1 >> 16);
        wt[idx + 8192]  = (unsigned short)(h2 >> 16);
        wt[idx + 16384] = (unsigned short)(h3 >> 16);
    }
    __syncthreads();

    float  b1v[4];
    float2 w2v[4];
#pragma unroll
    for (int nt = 0; nt < 4; ++nt) {
        b1v[nt] = b1[nt * 16 + col];
        w2v[nt] = *(const float2*)(W2 + (size_t)(nt * 16 + col) * 2);
    }
    const float2 b2v = *(const float2*)b2;

    const int rowW = blockIdx.x * 512 + wv * 64;     // this wave's 64 rows
    const int r    = rowW + lane;

    const float2 g2 = *(const float2*)(gumbel_u + (size_t)r * 2);  // early

    float l0 = 0.f, l1 = 0.f;

    // prologue: prefetch (mt=0, ks=0). Lane reads row rowW+mt*16+col,
    // k = ks*32 + quad*8 .. +8 (two float4s).
    float4 r0 = *(const float4*)(slots + (size_t)(rowW + col) * D + quad * 8);
    float4 r1 = *(const float4*)(slots + (size_t)(rowW + col) * D + quad * 8 + 4);

#pragma unroll
    for (int mt = 0; mt < 4; ++mt) {
        f32x4 acc[4];
#pragma unroll
        for (int nt = 0; nt < 4; ++nt) acc[nt] = f32x4{0.f, 0.f, 0.f, 0.f};

#pragma unroll
        for (int ks = 0; ks < 4; ++ks) {
            // split current raw -> 3 bf16 A-fragments, pure SSA (no memory)
            unsigned x1, x2, x3, y1, y2, y3;
            split3(r0.x, x1, x2, x3); split3(r0.y, y1, y2, y3);
            const int a10 = pack2(x1, y1), a20 = pack2(x2, y2), a30 = pack2(x3, y3);
            split3(r0.z, x1, x2, x3); split3(r0.w, y1, y2, y3);
            const int a11 = pack2(x1, y1), a21 = pack2(x2, y2), a31 = pack2(x3, y3);
            split3(r1.x, x1, x2, x3); split3(r1.y, y1, y2, y3);
            const int a12 = pack2(x1, y1), a22 = pack2(x2, y2), a32 = pack2(x3, y3);
            split3(r1.z, x1, x2, x3); split3(r1.w, y1, y2, y3);
            const int a13 = pack2(x1, y1), a23 = pack2(x2, y2), a33 = pack2(x3, y3);
            const bf16x8 a1 = __builtin_bit_cast(bf16x8, i32x4{a10, a11, a12, a13});
            const bf16x8 a2 = __builtin_bit_cast(bf16x8, i32x4{a20, a21, a22, a23});
            const bf16x8 a3 = __builtin_bit_cast(bf16x8, i32x4{a30, a31, a32, a33});

            // prefetch next (mt,ks) step — overlaps B reads + MFMAs below
            if (mt * 4 + ks < 15) {
                const int nmt = (ks < 3) ? mt : mt + 1;
                const int nks = (ks < 3) ? ks + 1 : 0;
                const float* np = slots + (size_t)(rowW + nmt * 16 + col) * D
                                        + nks * 32 + quad * 8;
                r0 = *(const float4*)np;
                r1 = *(const float4*)(np + 4);
            }

            // B fragments from LDS planes + 6-term MFMA
#pragma unroll
            for (int nt = 0; nt < 4; ++nt) {
                const int j = nt * 16 + col;
                const int chunk = (ks * 4 + quad) ^ col;
                const unsigned short* wp = &wt[j * 128 + chunk * 8];
                const bf16x8 bq1 = *(const bf16x8*)(wp);
                const bf16x8 bq2 = *(const bf16x8*)(wp + 8192);
                const bf16x8 bq3 = *(const bf16x8*)(wp + 16384);
                f32x4 c = acc[nt];
                c = __builtin_amdgcn_mfma_f32_16x16x32_bf16(a1, bq1, c, 0, 0, 0);
                c = __builtin_amdgcn_mfma_f32_16x16x32_bf16(a2, bq1, c, 0, 0, 0);
                c = __builtin_amdgcn_mfma_f32_16x16x32_bf16(a1, bq2, c, 0, 0, 0);
                c = __builtin_amdgcn_mfma_f32_16x16x32_bf16(a2, bq2, c, 0, 0, 0);
                c = __builtin_amdgcn_mfma_f32_16x16x32_bf16(a1, bq3, c, 0, 0, 0);
                c = __builtin_amdgcn_mfma_f32_16x16x32_bf16(a3, bq1, c, 0, 0, 0);
                acc[nt] = c;
            }
        }

        // ---- mt epilogue: layer2 + col-reduction, pure shuffles ----
        // C layout: col(j) = lane&15, local row = quad*4 + reg (within mt).
#pragma unroll
        for (int reg = 0; reg < 4; ++reg) {
            float q0 = 0.f, q1 = 0.f;
#pragma unroll
            for (int nt = 0; nt < 4; ++nt) {
                const float h = fmaxf(acc[nt][reg] + b1v[nt], 0.f);
                q0 = fmaf(h, w2v[nt].x, q0);
                q1 = fmaf(h, w2v[nt].y, q1);
            }
#pragma unroll
            for (int m = 1; m <= 8; m <<= 1) {
                q0 += __shfl_xor(q0, m, 64);
                q1 += __shfl_xor(q1, m, 64);
            }
            // lane L (row rowW+L) needs mt=L>>4, reg=L&3, from quad (L>>2)&3
            const int src = (((lane >> 2) & 3) << 4) | (lane & 15);
            const float g0 = __shfl(q0, src, 64);
            const float g1 = __shfl(q1, src, 64);
            if (((lane >> 4) == mt) && ((lane & 3) == reg)) { l0 = g0; l1 = g1; }
        }
    }

    l0 += b2v.x; l1 += b2v.y;

    // ---- gumbel decision + keep prob ----
    const float lo = 1e-10f, hi = (float)(1.0 - 1e-7);
    const float u0 = fminf(fmaxf(g2.x, lo), hi);
    const float u1 = fminf(fmaxf(g2.y, lo), hi);
    const float gn0 = -logf(-logf(u0));
    const float gn1 = -logf(-logf(u1));
    float dec = ((l1 + gn1) > (l0 + gn0)) ? 1.0f : 0.0f;   // tie -> idx0 -> 0

    const float m  = fmaxf(l0, l1);
    const float e0 = expf(l0 - m), e1 = expf(l1 - m);
    const float keep = e1 / (e0 + e1);

    // ensure-minimum: wave == one b; fires only if no slot active
    const unsigned long long act = __ballot(dec != 0.0f);
    if (act == 0ull) {
        float v = fix_u[r];
        int  idx = lane;
#pragma unroll
        for (int off = 32; off > 0; off >>= 1) {
            const float ov  = __shfl_xor(v, off, 64);
            const int  oidx = __shfl_xor(idx, off, 64);
            if (ov > v || (ov == v && oidx < idx)) { v = ov; idx = oidx; }
        }
        if (lane == idx) dec = 1.0f;
    }

    out[r] = dec;
    out[NROWS + r] = keep;
}

extern "C" void kernel_launch(void* const* d_in, const int* in_sizes, int n_in,
                              void* d_out, int out_size, void* d_ws, size_t ws_size,
                              hipStream_t stream)
{
    const float* slots  = (const float*)d_in[0];
    const float* gumbel = (const float*)d_in[1];
    const float* fixu   = (const float*)d_in[2];
    const float* W1     = (const float*)d_in[3];
    const float* b1     = (const float*)d_in[4];
    const float* W2     = (const float*)d_in[5];
    const float* b2     = (const float*)d_in[6];
    float* out = (float*)d_out;

    gumbel_slot_mfma<<<1024, 512, 0, stream>>>(
        slots, gumbel, fixu, W1, b1, W2, b2, out);
}